// Round 2
// baseline (152.661 us; speedup 1.0000x reference)
//
#include <hip/hip_runtime.h>
#include <math.h>

#define N_HARM 80
#define HOP 240
#define NUM_NOTES 8

#define TWO_PI_D     6.283185307179586476925286766559
#define INV_TWO_PI_D 0.15915494309189533576888376337251

// Reduce x (>= 0, < ~1e7) into [0, 2pi) in double. Error ~1e-12 rad.
static __device__ __forceinline__ double reduce_2pi(double x) {
    double q = floor(x * INV_TWO_PI_D);
    return x - q * TWO_PI_D;
}

// Kernel 1: phases[b,t,h] = (initial_phase[b,h] + exclusive_cumsum_t(phase_inc)) mod 2pi
// Computed entirely in f64 (truth-mode), stored as f32 in [0, 2pi).
__global__ void phase_kernel(const float* __restrict__ f0,         // (B,T)
                             const float* __restrict__ init_phase, // (B,80)
                             float* __restrict__ phases,           // (B,T,80)
                             int B, int T) {
    int gid = blockIdx.x * blockDim.x + threadIdx.x;
    if (gid >= B * N_HARM) return;
    int b = gid / N_HARM;
    int h = gid % N_HARM;
    const double hm = (double)(h + 1);
    const double C = TWO_PI_D * 0.01;   // 2pi * HOP/SR
    const float* f0b = f0 + (size_t)b * T;
    float* pb = phases + ((size_t)b * T) * N_HARM + h;

    double running = reduce_2pi((double)init_phase[b * N_HARM + h]);
    for (int t = 0; t < T; ++t) {
        pb[(size_t)t * N_HARM] = (float)running;
        double inc = C * ((double)f0b[t] * hm);
        running = reduce_2pi(running + inc);   // keep magnitude small; exact mod math
    }
}

// Kernel 2: one thread per output sample (b, s).
__global__ void __launch_bounds__(256)
synth_kernel(const float* __restrict__ f0,        // (B,T)
             const float* __restrict__ harm_amp,  // (B,T,80)
             const float* __restrict__ vmix,      // (B,T)
             const float* __restrict__ adsr,      // (B,T,4)
             const int*   __restrict__ note_on,   // (B,8)
             const int*   __restrict__ note_off,  // (B,8)
             const float* __restrict__ phases,    // (B,T,80)
             float* __restrict__ out,             // (B,duration)
             int T, int duration) {
    int s = blockIdx.x * blockDim.x + threadIdx.x;
    int b = blockIdx.y;
    if (s >= duration) return;

    const float sf = (float)s;

    // ---- ADSR envelope: notes applied in order, later regions override ----
    float env = 0.0f;
    const int nfe = duration / HOP + 1;   // n_frames_env
    for (int n = 0; n < NUM_NOTES; ++n) {
        int on  = note_on [b * NUM_NOTES + n];
        int off = note_off[b * NUM_NOTES + n];
        int nsi = on * HOP;
        if (!(nsi >= 0 && nsi < duration)) continue;   // valid
        int ne = min(off * HOP, duration);
        int onset = min(on, nfe - 1);
        onset = min(onset, T - 1);        // safety clamp (no-op for given data)
        const float* p = adsr + ((size_t)b * T + onset) * 4;
        // p*SR is exact in f64 (24-bit mantissa * 15-bit int), so floor is truth.
        int a_n = (int)floor((double)p[0] * 24000.0);
        int d_n = (int)floor((double)p[1] * 24000.0);
        float sus = p[2];
        int r_n = (int)floor((double)p[3] * 24000.0);
        int a_end = min(nsi + a_n, duration);
        int d_end = min(a_end + d_n, duration);
        int r_end = min(ne + r_n, duration);
        if (s >= nsi   && s < a_end) env = (sf - (float)nsi) / (float)max(a_n, 1);
        if (s >= a_end && s < d_end) env = 1.0f - ((1.0f - sus) * (sf - (float)a_end)) / (float)max(d_n, 1);
        if (s >= d_end && s < ne)    env = sus;
        if (s >= ne    && s < r_end) env = sus * (1.0f - (sf - (float)ne) / (float)max(r_n, 1));
    }

    // ---- linear-interp indices/weights (f64 coord; exact boundary behavior) ----
    double coord = ((double)s + 0.5) * ((double)T / (double)duration) - 0.5;
    coord = fmax(coord, 0.0);
    int i0 = (int)floor(coord);
    int i1 = min(i0 + 1, T - 1);
    float w   = (float)(coord - (double)i0);
    float omw = 1.0f - w;

    // ---- harmonic sum: f64-accurate argument, reduced mod 2pi ----
    int frame = min(s / HOP, T - 1);
    const float f0v = f0[(size_t)b * T + frame];
    // base = (2pi * f0 * t) mod 2pi, in f64; t = s / SR
    double t_d = (double)s * (1.0 / 24000.0);
    float basef = (float)reduce_2pi(TWO_PI_D * (double)f0v * t_d);

    const float4* ph4 = (const float4*)(phases   + ((size_t)b * T + frame) * N_HARM);
    const float4* A04 = (const float4*)(harm_amp + ((size_t)b * T + i0)    * N_HARM);
    const float4* A14 = (const float4*)(harm_amp + ((size_t)b * T + i1)    * N_HARM);

    float acc = 0.0f;
#pragma unroll 4
    for (int q = 0; q < N_HARM / 4; ++q) {
        float4 ph = ph4[q];
        float4 a0 = A04[q];
        float4 a1 = A14[q];
        float hb = (float)(4 * q);
        {
            float v = basef * (hb + 1.0f) + ph.x;   // |v| <= ~509
            acc += sinf(v) * (a0.x * omw + a1.x * w);
        }
        {
            float v = basef * (hb + 2.0f) + ph.y;
            acc += sinf(v) * (a0.y * omw + a1.y * w);
        }
        {
            float v = basef * (hb + 3.0f) + ph.z;
            acc += sinf(v) * (a0.z * omw + a1.z * w);
        }
        {
            float v = basef * (hb + 4.0f) + ph.w;
            acc += sinf(v) * (a0.w * omw + a1.w * w);
        }
    }

    float vmv = vmix[(size_t)b * T + i0] * omw + vmix[(size_t)b * T + i1] * w;
    out[(size_t)b * duration + s] = acc * env * vmv;
}

extern "C" void kernel_launch(void* const* d_in, const int* in_sizes, int n_in,
                              void* d_out, int out_size, void* d_ws, size_t ws_size,
                              hipStream_t stream) {
    const float* f0   = (const float*)d_in[0];
    const float* ha   = (const float*)d_in[1];
    const float* vm   = (const float*)d_in[2];
    const float* adsr = (const float*)d_in[3];
    const float* ip   = (const float*)d_in[4];
    const int*   non  = (const int*)d_in[5];
    const int*   noff = (const int*)d_in[6];

    int B = in_sizes[4] / N_HARM;      // initial_phase is (B, 80)
    int T = in_sizes[0] / B;           // f0 is (B, T)
    int duration = out_size / B;       // out is (B, duration)

    float* phases = (float*)d_ws;      // (B,T,80) fp32 = 640 KB for B=4,T=500

    int pth = B * N_HARM;
    phase_kernel<<<dim3((pth + 63) / 64), dim3(64), 0, stream>>>(f0, ip, phases, B, T);

    dim3 grid((duration + 255) / 256, B);
    synth_kernel<<<grid, dim3(256), 0, stream>>>(f0, ha, vm, adsr, non, noff, phases,
                                                 (float*)d_out, T, duration);
}

// Round 3
// 89.175 us; speedup vs baseline: 1.7119x; 1.7119x over previous
//
#include <hip/hip_runtime.h>
#include <math.h>

#define N_HARM 80
#define HOP 240
#define NUM_NOTES 8

#define TWO_PI_D     6.283185307179586476925286766559
#define INV_TWO_PI_D 0.15915494309189533576888376337251

// exact for x in [0,2): floor is 0 or 1, subtraction exact
static __device__ __forceinline__ float fract1(float x) { return x - floorf(x); }

// Kernel 1: per-batch wave-scan.
//   S_rev[b,t] = exclusive_cumsum_t( f0[b,t] * 0.01 )   (f64, revolutions)
//   ip_rev[b,h] = (initial_phase[b,h] / 2pi) mod 1      (f32, revolutions)
// One 64-thread block per batch.
__global__ void __launch_bounds__(64)
scan_kernel(const float* __restrict__ f0,         // (B,T)
            const float* __restrict__ init_phase, // (B,80)
            double* __restrict__ S_rev,           // (B,T)
            float*  __restrict__ ip_rev,          // (B,80)
            int T) {
    int b = blockIdx.x;
    int lane = threadIdx.x;               // 0..63
    int chunk = (T + 63) / 64;
    int start = lane * chunk;
    int end   = min(start + chunk, T);

    const float* f0b = f0 + (size_t)b * T;

    // pass 1: per-lane total
    double local = 0.0;
    for (int t = start; t < end; ++t) local += (double)f0b[t] * 0.01;

    // inclusive wave scan (f64 via __shfl_up)
    double incl = local;
    for (int off = 1; off < 64; off <<= 1) {
        double n = __shfl_up(incl, off, 64);
        if (lane >= off) incl += n;
    }
    double run = incl - local;            // exclusive base for this lane

    // pass 2: write exclusive prefix
    double* Sb = S_rev + (size_t)b * T;
    for (int t = start; t < end; ++t) {
        Sb[t] = run;
        run += (double)f0b[t] * 0.01;
    }

    // initial phase -> revolutions in [0,1)
    for (int h = lane; h < N_HARM; h += 64) {
        double x = (double)init_phase[b * N_HARM + h] * INV_TWO_PI_D;
        x -= floor(x);
        ip_rev[b * N_HARM + h] = (float)x;
    }
}

// Kernel 2: one thread per output sample (b, s).
__global__ void __launch_bounds__(256)
synth_kernel(const float* __restrict__ f0,        // (B,T)
             const float* __restrict__ harm_amp,  // (B,T,80)
             const float* __restrict__ vmix,      // (B,T)
             const float* __restrict__ adsr,      // (B,T,4)
             const int*   __restrict__ note_on,   // (B,8)
             const int*   __restrict__ note_off,  // (B,8)
             const double* __restrict__ S_rev,    // (B,T)
             const float*  __restrict__ ip_rev,   // (B,80)
             float* __restrict__ out,             // (B,duration)
             int T, int duration) {
    int s = blockIdx.x * blockDim.x + threadIdx.x;
    int b = blockIdx.y;
    if (s >= duration) return;

    const float sf = (float)s;

    // ---- ADSR envelope: notes applied in order, later regions override ----
    float env = 0.0f;
    const int nfe = duration / HOP + 1;
    for (int n = 0; n < NUM_NOTES; ++n) {
        int on  = note_on [b * NUM_NOTES + n];
        int off = note_off[b * NUM_NOTES + n];
        int nsi = on * HOP;
        if (!(nsi >= 0 && nsi < duration)) continue;
        int ne = min(off * HOP, duration);
        int onset = min(min(on, nfe - 1), T - 1);
        const float* p = adsr + ((size_t)b * T + onset) * 4;
        int a_n = (int)floor((double)p[0] * 24000.0);   // exact in f64
        int d_n = (int)floor((double)p[1] * 24000.0);
        float sus = p[2];
        int r_n = (int)floor((double)p[3] * 24000.0);
        int a_end = min(nsi + a_n, duration);
        int d_end = min(a_end + d_n, duration);
        int r_end = min(ne + r_n, duration);
        if (s >= nsi   && s < a_end) env = (sf - (float)nsi) / (float)max(a_n, 1);
        if (s >= a_end && s < d_end) env = 1.0f - ((1.0f - sus) * (sf - (float)a_end)) / (float)max(d_n, 1);
        if (s >= d_end && s < ne)    env = sus;
        if (s >= ne    && s < r_end) env = sus * (1.0f - (sf - (float)ne) / (float)max(r_n, 1));
    }

    // ---- linear-interp indices/weights (f64 coord; exact boundary behavior) ----
    double coord = ((double)s + 0.5) * ((double)T / (double)duration) - 0.5;
    coord = fmax(coord, 0.0);
    int i0 = (int)floor(coord);
    int i1 = min(i0 + 1, T - 1);
    float w   = (float)(coord - (double)i0);
    float omw = 1.0f - w;

    // ---- per-sample phase base, in revolutions, reduced mod 1 in f64 ----
    int frame = min(s / HOP, T - 1);
    const float f0v = f0[(size_t)b * T + frame];
    double p_rev = (double)f0v * ((double)s * (1.0 / 24000.0)) + S_rev[(size_t)b * T + frame];
    p_rev -= floor(p_rev);                       // [0,1), error ~1e-12
    const float psi = (float)p_rev;              // cast err ~6e-8 rev

    const float4* A04 = (const float4*)(harm_amp + ((size_t)b * T + i0) * N_HARM);
    const float4* A14 = (const float4*)(harm_amp + ((size_t)b * T + i1) * N_HARM);
    const float4* IP4 = (const float4*)(ip_rev + (size_t)b * N_HARM);

    // hp_h = fract(h * psi) via recurrence (keeps argument in [0,1), ~1e-6 rev err)
    float hp = 0.0f;
    float acc = 0.0f;
#pragma unroll 5
    for (int q = 0; q < N_HARM / 4; ++q) {
        float4 a0 = A04[q];
        float4 a1 = A14[q];
        float4 ip = IP4[q];
        float s0, s1, s2, s3;
        hp = fract1(hp + psi); s0 = __builtin_amdgcn_sinf(hp + ip.x);  // v_sin_f32: sin(x*2pi)
        hp = fract1(hp + psi); s1 = __builtin_amdgcn_sinf(hp + ip.y);
        hp = fract1(hp + psi); s2 = __builtin_amdgcn_sinf(hp + ip.z);
        hp = fract1(hp + psi); s3 = __builtin_amdgcn_sinf(hp + ip.w);
        acc += s0 * (a0.x * omw + a1.x * w);
        acc += s1 * (a0.y * omw + a1.y * w);
        acc += s2 * (a0.z * omw + a1.z * w);
        acc += s3 * (a0.w * omw + a1.w * w);
    }

    float vmv = vmix[(size_t)b * T + i0] * omw + vmix[(size_t)b * T + i1] * w;
    out[(size_t)b * duration + s] = acc * env * vmv;
}

extern "C" void kernel_launch(void* const* d_in, const int* in_sizes, int n_in,
                              void* d_out, int out_size, void* d_ws, size_t ws_size,
                              hipStream_t stream) {
    const float* f0   = (const float*)d_in[0];
    const float* ha   = (const float*)d_in[1];
    const float* vm   = (const float*)d_in[2];
    const float* adsr = (const float*)d_in[3];
    const float* ip   = (const float*)d_in[4];
    const int*   non  = (const int*)d_in[5];
    const int*   noff = (const int*)d_in[6];

    int B = in_sizes[4] / N_HARM;      // initial_phase is (B, 80)
    int T = in_sizes[0] / B;           // f0 is (B, T)
    int duration = out_size / B;       // out is (B, duration)

    // workspace layout: S_rev (B*T doubles), then ip_rev (B*80 floats)
    double* S_rev  = (double*)d_ws;
    float*  ip_rev = (float*)((char*)d_ws + (size_t)B * T * sizeof(double));

    scan_kernel<<<dim3(B), dim3(64), 0, stream>>>(f0, ip, S_rev, ip_rev, T);

    dim3 grid((duration + 255) / 256, B);
    synth_kernel<<<grid, dim3(256), 0, stream>>>(f0, ha, vm, adsr, non, noff,
                                                 S_rev, ip_rev,
                                                 (float*)d_out, T, duration);
}

// Round 4
// 87.923 us; speedup vs baseline: 1.7363x; 1.0142x over previous
//
#include <hip/hip_runtime.h>
#include <math.h>

#define N_HARM 80
#define HOP 240
#define NUM_NOTES 8

#define TWO_PI_D     6.283185307179586476925286766559
#define INV_TWO_PI_D 0.15915494309189533576888376337251

// exact for x in [0, 2^23): result in [0,1)
static __device__ __forceinline__ float fract1(float x) { return x - floorf(x); }

// Kernel 1: per-batch wave-scan.
//   S_rev[b,t] = exclusive_cumsum_t( f0[b,t] * 0.01 )   (f64, revolutions)
//   ip_rev[b,h] = (initial_phase[b,h] / 2pi) mod 1      (f32, revolutions)
__global__ void __launch_bounds__(64)
scan_kernel(const float* __restrict__ f0,         // (B,T)
            const float* __restrict__ init_phase, // (B,80)
            double* __restrict__ S_rev,           // (B,T)
            float*  __restrict__ ip_rev,          // (B,80)
            int T) {
    int b = blockIdx.x;
    int lane = threadIdx.x;               // 0..63
    int chunk = (T + 63) / 64;
    int start = lane * chunk;
    int end   = min(start + chunk, T);

    const float* f0b = f0 + (size_t)b * T;

    double local = 0.0;
    for (int t = start; t < end; ++t) local += (double)f0b[t] * 0.01;

    double incl = local;
    for (int off = 1; off < 64; off <<= 1) {
        double n = __shfl_up(incl, off, 64);
        if (lane >= off) incl += n;
    }
    double run = incl - local;            // exclusive base for this lane

    double* Sb = S_rev + (size_t)b * T;
    for (int t = start; t < end; ++t) {
        Sb[t] = run;
        run += (double)f0b[t] * 0.01;
    }

    for (int h = lane; h < N_HARM; h += 64) {
        double x = (double)init_phase[b * N_HARM + h] * INV_TWO_PI_D;
        x -= floor(x);
        ip_rev[b * N_HARM + h] = (float)x;
    }
}

// Kernel 2: one thread per output sample (b, s).
__global__ void __launch_bounds__(256)
synth_kernel(const float* __restrict__ f0,        // (B,T)
             const float* __restrict__ harm_amp,  // (B,T,80)
             const float* __restrict__ vmix,      // (B,T)
             const float* __restrict__ adsr,      // (B,T,4)
             const int*   __restrict__ note_on,   // (B,8)
             const int*   __restrict__ note_off,  // (B,8)
             const double* __restrict__ S_rev,    // (B,T)
             const float*  __restrict__ ip_rev,   // (B,80)
             float* __restrict__ out,             // (B,duration)
             int T, int duration) {
    int s = blockIdx.x * blockDim.x + threadIdx.x;
    int b = blockIdx.y;
    if (s >= duration) return;

    const float sf = (float)s;

    // ---- ADSR envelope: notes applied in order, later regions override ----
    float env = 0.0f;
    const int nfe = duration / HOP + 1;
    for (int n = 0; n < NUM_NOTES; ++n) {
        int on  = note_on [b * NUM_NOTES + n];
        int off = note_off[b * NUM_NOTES + n];
        int nsi = on * HOP;
        if (!(nsi >= 0 && nsi < duration)) continue;
        int ne = min(off * HOP, duration);
        int onset = min(min(on, nfe - 1), T - 1);
        const float* p = adsr + ((size_t)b * T + onset) * 4;
        int a_n = (int)floor((double)p[0] * 24000.0);   // exact in f64
        int d_n = (int)floor((double)p[1] * 24000.0);
        float sus = p[2];
        int r_n = (int)floor((double)p[3] * 24000.0);
        int a_end = min(nsi + a_n, duration);
        int d_end = min(a_end + d_n, duration);
        int r_end = min(ne + r_n, duration);
        if (s >= nsi   && s < a_end) env = (sf - (float)nsi) / (float)max(a_n, 1);
        if (s >= a_end && s < d_end) env = 1.0f - ((1.0f - sus) * (sf - (float)a_end)) / (float)max(d_n, 1);
        if (s >= d_end && s < ne)    env = sus;
        if (s >= ne    && s < r_end) env = sus * (1.0f - (sf - (float)ne) / (float)max(r_n, 1));
    }

    // ---- linear-interp indices/weights (f64 coord; exact boundary behavior) ----
    double coord = ((double)s + 0.5) * ((double)T / (double)duration) - 0.5;
    coord = fmax(coord, 0.0);
    int i0 = (int)floor(coord);
    int i1 = min(i0 + 1, T - 1);
    float w   = (float)(coord - (double)i0);
    float omw = 1.0f - w;

    // ---- per-sample phase base, in revolutions, reduced mod 1 in f64 ----
    int frame = min(s / HOP, T - 1);
    const float f0v = f0[(size_t)b * T + frame];
    double p_rev = (double)f0v * ((double)s * (1.0 / 24000.0)) + S_rev[(size_t)b * T + frame];
    p_rev -= floor(p_rev);                       // [0,1), error ~1e-12
    const float psi = (float)p_rev;              // cast err ~6e-8 rev

    const float4* A04 = (const float4*)(harm_amp + ((size_t)b * T + i0) * N_HARM);
    const float4* A14 = (const float4*)(harm_amp + ((size_t)b * T + i1) * N_HARM);
    const float4* IP4 = (const float4*)(ip_rev + (size_t)b * N_HARM);

    // Independent per harmonic: arg = fract(h*psi) + ip[h]  in [0,2) revolutions.
    // No loop-carried chain; 4 accumulators for ILP.
    float acc0 = 0.0f, acc1 = 0.0f, acc2 = 0.0f, acc3 = 0.0f;
#pragma unroll 4
    for (int q = 0; q < N_HARM / 4; ++q) {
        float4 a0 = A04[q];
        float4 a1 = A14[q];
        float4 ip = IP4[q];
        float hb = (float)(4 * q);
        float v0 = fract1((hb + 1.0f) * psi) + ip.x;
        float v1 = fract1((hb + 2.0f) * psi) + ip.y;
        float v2 = fract1((hb + 3.0f) * psi) + ip.z;
        float v3 = fract1((hb + 4.0f) * psi) + ip.w;
        float s0 = __builtin_amdgcn_sinf(v0);   // v_sin_f32: sin(2*pi*x)
        float s1 = __builtin_amdgcn_sinf(v1);
        float s2 = __builtin_amdgcn_sinf(v2);
        float s3 = __builtin_amdgcn_sinf(v3);
        float m0 = fmaf(a0.x, omw, a1.x * w);
        float m1 = fmaf(a0.y, omw, a1.y * w);
        float m2 = fmaf(a0.z, omw, a1.z * w);
        float m3 = fmaf(a0.w, omw, a1.w * w);
        acc0 = fmaf(s0, m0, acc0);
        acc1 = fmaf(s1, m1, acc1);
        acc2 = fmaf(s2, m2, acc2);
        acc3 = fmaf(s3, m3, acc3);
    }
    float acc = (acc0 + acc1) + (acc2 + acc3);

    float vmv = vmix[(size_t)b * T + i0] * omw + vmix[(size_t)b * T + i1] * w;
    out[(size_t)b * duration + s] = acc * env * vmv;
}

extern "C" void kernel_launch(void* const* d_in, const int* in_sizes, int n_in,
                              void* d_out, int out_size, void* d_ws, size_t ws_size,
                              hipStream_t stream) {
    const float* f0   = (const float*)d_in[0];
    const float* ha   = (const float*)d_in[1];
    const float* vm   = (const float*)d_in[2];
    const float* adsr = (const float*)d_in[3];
    const float* ip   = (const float*)d_in[4];
    const int*   non  = (const int*)d_in[5];
    const int*   noff = (const int*)d_in[6];

    int B = in_sizes[4] / N_HARM;      // initial_phase is (B, 80)
    int T = in_sizes[0] / B;           // f0 is (B, T)
    int duration = out_size / B;       // out is (B, duration)

    // workspace layout: S_rev (B*T doubles), then ip_rev (B*80 floats)
    double* S_rev  = (double*)d_ws;
    float*  ip_rev = (float*)((char*)d_ws + (size_t)B * T * sizeof(double));

    scan_kernel<<<dim3(B), dim3(64), 0, stream>>>(f0, ip, S_rev, ip_rev, T);

    dim3 grid((duration + 255) / 256, B);
    synth_kernel<<<grid, dim3(256), 0, stream>>>(f0, ha, vm, adsr, non, noff,
                                                 S_rev, ip_rev,
                                                 (float*)d_out, T, duration);
}

// Round 5
// 86.669 us; speedup vs baseline: 1.7614x; 1.0145x over previous
//
#include <hip/hip_runtime.h>
#include <math.h>

#define N_HARM 80
#define HOP 240
#define NUM_NOTES 8

#define TWO_PI_D     6.283185307179586476925286766559
#define INV_TWO_PI_D 0.15915494309189533576888376337251

// exact for x in [0, 2^23): result in [0,1)
static __device__ __forceinline__ float fract1(float x) { return x - floorf(x); }

// Kernel 1: per-batch setup (one 64-thread block per batch).
//  - S_rev[b,t]  = exclusive_cumsum_t( f0[b,t] * 0.01 )  (f64, revolutions)
//  - ip_rev[b,h] = (initial_phase[b,h] / 2pi) mod 1      (f32, revolutions)
//  - note_pre[b,n] = 12 floats of precomputed ADSR region constants
__global__ void __launch_bounds__(64)
setup_kernel(const float* __restrict__ f0,         // (B,T)
             const float* __restrict__ init_phase, // (B,80)
             const float* __restrict__ adsr,       // (B,T,4)
             const int*   __restrict__ note_on,    // (B,8)
             const int*   __restrict__ note_off,   // (B,8)
             double* __restrict__ S_rev,           // (B,T)
             float*  __restrict__ ip_rev,          // (B,80)
             float*  __restrict__ note_pre,        // (B,8,12)
             int T, int duration) {
    int b = blockIdx.x;
    int lane = threadIdx.x;               // 0..63
    int chunk = (T + 63) / 64;
    int start = lane * chunk;
    int end   = min(start + chunk, T);

    const float* f0b = f0 + (size_t)b * T;

    // ---- f64 exclusive scan of f0*0.01 across the wave ----
    double local = 0.0;
    for (int t = start; t < end; ++t) local += (double)f0b[t] * 0.01;

    double incl = local;
    for (int off = 1; off < 64; off <<= 1) {
        double n = __shfl_up(incl, off, 64);
        if (lane >= off) incl += n;
    }
    double run = incl - local;            // exclusive base for this lane

    double* Sb = S_rev + (size_t)b * T;
    for (int t = start; t < end; ++t) {
        Sb[t] = run;
        run += (double)f0b[t] * 0.01;
    }

    // ---- initial phase -> revolutions in [0,1) ----
    for (int h = lane; h < N_HARM; h += 64) {
        double x = (double)init_phase[b * N_HARM + h] * INV_TWO_PI_D;
        x -= floor(x);
        ip_rev[b * N_HARM + h] = (float)x;
    }

    // ---- ADSR per-note constants (lanes 0..7) ----
    if (lane < NUM_NOTES) {
        int n = lane;
        int on  = note_on [b * NUM_NOTES + n];
        int off = note_off[b * NUM_NOTES + n];
        int nsi = on * HOP;
        float ns_f, aend_f, dend_f, ne_f, rend_f, inv_a, c_dec, sus, s_rel;
        if (nsi >= 0 && nsi < duration) {
            int ne  = min(off * HOP, duration);
            int nfe = duration / HOP + 1;
            int onset = min(min(on, nfe - 1), T - 1);
            const float* p = adsr + ((size_t)b * T + onset) * 4;
            int a_n = (int)floor((double)p[0] * 24000.0);   // exact in f64
            int d_n = (int)floor((double)p[1] * 24000.0);
            sus = p[2];
            int r_n = (int)floor((double)p[3] * 24000.0);
            int a_end = min(nsi + a_n, duration);
            int d_end = min(a_end + d_n, duration);
            int r_end = min(ne + r_n, duration);
            ns_f   = (float)nsi;     // all < 2^23: exact in f32
            aend_f = (float)a_end;
            dend_f = (float)d_end;
            ne_f   = (float)ne;
            rend_f = (float)r_end;
            inv_a  = 1.0f / (float)max(a_n, 1);
            c_dec  = (1.0f - sus) / (float)max(d_n, 1);
            s_rel  = sus / (float)max(r_n, 1);
        } else {
            ns_f = aend_f = dend_f = ne_f = rend_f = -1.0f;  // empty ranges
            inv_a = c_dec = sus = s_rel = 0.0f;
        }
        float* q = note_pre + ((size_t)b * NUM_NOTES + n) * 12;
        q[0] = ns_f;  q[1] = aend_f; q[2]  = dend_f; q[3]  = ne_f;
        q[4] = rend_f; q[5] = inv_a; q[6]  = c_dec;  q[7]  = sus;
        q[8] = s_rel; q[9] = 0.0f;   q[10] = 0.0f;   q[11] = 0.0f;
    }
}

// Kernel 2: one thread per output sample (b, s).
__global__ void __launch_bounds__(256)
synth_kernel(const float* __restrict__ f0,        // (B,T)
             const float* __restrict__ harm_amp,  // (B,T,80)
             const float* __restrict__ vmix,      // (B,T)
             const double* __restrict__ S_rev,    // (B,T)
             const float*  __restrict__ ip_rev,   // (B,80)
             const float*  __restrict__ note_pre, // (B,8,12)
             float* __restrict__ out,             // (B,duration)
             int T, int duration) {
    int s = blockIdx.x * blockDim.x + threadIdx.x;
    int b = blockIdx.y;
    if (s >= duration) return;

    const float sf = (float)s;

    // ---- ADSR from precomputed constants (wave-uniform loads, no f64) ----
    float env = 0.0f;
    const float* npb = note_pre + (size_t)b * NUM_NOTES * 12;
#pragma unroll
    for (int n = 0; n < NUM_NOTES; ++n) {
        const float4* c = (const float4*)(npb + n * 12);
        float4 c0 = c[0];   // ns, a_end, d_end, ne
        float4 c1 = c[1];   // r_end, inv_a, c_dec, sus
        float  sr = npb[n * 12 + 8];
        env = (sf >= c0.x && sf < c0.y) ? (sf - c0.x) * c1.y          : env;
        env = (sf >= c0.y && sf < c0.z) ? 1.0f - c1.z * (sf - c0.y)   : env;
        env = (sf >= c0.z && sf < c0.w) ? c1.w                        : env;
        env = (sf >= c0.w && sf < c1.x) ? c1.w - sr * (sf - c0.w)     : env;
    }

    // ---- linear-interp indices/weights (f64 coord; exact boundary behavior) ----
    double coord = ((double)s + 0.5) * ((double)T / (double)duration) - 0.5;
    coord = fmax(coord, 0.0);
    int i0 = (int)floor(coord);
    int i1 = min(i0 + 1, T - 1);
    float w   = (float)(coord - (double)i0);
    float omw = 1.0f - w;

    // ---- per-sample phase base, revolutions mod 1, f64-accurate ----
    int frame = min(s / HOP, T - 1);
    const float f0v = f0[(size_t)b * T + frame];
    double p_rev = (double)f0v * ((double)s * (1.0 / 24000.0)) + S_rev[(size_t)b * T + frame];
    p_rev -= floor(p_rev);                       // [0,1), error ~1e-12
    const float psi = (float)p_rev;              // cast err ~6e-8 rev

    const float4* A04 = (const float4*)(harm_amp + ((size_t)b * T + i0) * N_HARM);
    const float4* A14 = (const float4*)(harm_amp + ((size_t)b * T + i1) * N_HARM);
    const float4* IP4 = (const float4*)(ip_rev + (size_t)b * N_HARM);

    // arg_h = fract(h*psi + ip[h]) in [0,1) revolutions; v_sin_f32 = sin(2*pi*x).
    float acc0 = 0.0f, acc1 = 0.0f, acc2 = 0.0f, acc3 = 0.0f;
#pragma unroll 4
    for (int q = 0; q < N_HARM / 4; ++q) {
        float4 a0 = A04[q];
        float4 a1 = A14[q];
        float4 ip = IP4[q];
        float hb = (float)(4 * q);
        float v0 = fract1(fmaf(hb + 1.0f, psi, ip.x));
        float v1 = fract1(fmaf(hb + 2.0f, psi, ip.y));
        float v2 = fract1(fmaf(hb + 3.0f, psi, ip.z));
        float v3 = fract1(fmaf(hb + 4.0f, psi, ip.w));
        float s0 = __builtin_amdgcn_sinf(v0);
        float s1 = __builtin_amdgcn_sinf(v1);
        float s2 = __builtin_amdgcn_sinf(v2);
        float s3 = __builtin_amdgcn_sinf(v3);
        float m0 = fmaf(a0.x, omw, a1.x * w);
        float m1 = fmaf(a0.y, omw, a1.y * w);
        float m2 = fmaf(a0.z, omw, a1.z * w);
        float m3 = fmaf(a0.w, omw, a1.w * w);
        acc0 = fmaf(s0, m0, acc0);
        acc1 = fmaf(s1, m1, acc1);
        acc2 = fmaf(s2, m2, acc2);
        acc3 = fmaf(s3, m3, acc3);
    }
    float acc = (acc0 + acc1) + (acc2 + acc3);

    float vmv = vmix[(size_t)b * T + i0] * omw + vmix[(size_t)b * T + i1] * w;
    out[(size_t)b * duration + s] = acc * env * vmv;
}

extern "C" void kernel_launch(void* const* d_in, const int* in_sizes, int n_in,
                              void* d_out, int out_size, void* d_ws, size_t ws_size,
                              hipStream_t stream) {
    const float* f0   = (const float*)d_in[0];
    const float* ha   = (const float*)d_in[1];
    const float* vm   = (const float*)d_in[2];
    const float* adsr = (const float*)d_in[3];
    const float* ip   = (const float*)d_in[4];
    const int*   non  = (const int*)d_in[5];
    const int*   noff = (const int*)d_in[6];

    int B = in_sizes[4] / N_HARM;      // initial_phase is (B, 80)
    int T = in_sizes[0] / B;           // f0 is (B, T)
    int duration = out_size / B;       // out is (B, duration)

    // workspace: S_rev (B*T f64) | ip_rev (B*80 f32) | note_pre (B*8*12 f32)
    double* S_rev  = (double*)d_ws;
    float*  ip_rev = (float*)((char*)d_ws + (size_t)B * T * sizeof(double));
    float*  npre   = ip_rev + (size_t)B * N_HARM;

    setup_kernel<<<dim3(B), dim3(64), 0, stream>>>(f0, ip, adsr, non, noff,
                                                   S_rev, ip_rev, npre, T, duration);

    dim3 grid((duration + 255) / 256, B);
    synth_kernel<<<grid, dim3(256), 0, stream>>>(f0, ha, vm, S_rev, ip_rev, npre,
                                                 (float*)d_out, T, duration);
}